// Round 8
// baseline (335.301 us; speedup 1.0000x reference)
//
#include <hip/hip_runtime.h>
#include <stdint.h>

typedef unsigned short u16;
typedef __attribute__((ext_vector_type(8))) __bf16 bf16x8;
typedef __attribute__((ext_vector_type(4))) float f32x4;
typedef __attribute__((ext_vector_type(4))) u16 u16x4;
typedef __attribute__((ext_vector_type(4))) uint32_t u32x4;

__device__ __forceinline__ u16 f2bf(float f) {
    union { float f; uint32_t u; } v; v.f = f;
    uint32_t r = (v.u + 0x7fffu + ((v.u >> 16) & 1u)) >> 16;
    return (u16)r;
}

__device__ __forceinline__ void gll16(const u16* g, u16* l) {
    __builtin_amdgcn_global_load_lds((const __attribute__((address_space(1))) uint32_t*)g,
                                     (__attribute__((address_space(3))) uint32_t*)l, 16, 0, 0);
}

// ---------------- cast fp32 -> bf16 (x) ----------------
__global__ void cast_kernel(const float* __restrict__ in, u16* __restrict__ out, int n) {
    int i = (blockIdx.x * blockDim.x + threadIdx.x) * 4;
    if (i + 3 < n) {
        float4 v = *(const float4*)(in + i);
        u16x4 o;
        o.x = f2bf(v.x); o.y = f2bf(v.y); o.z = f2bf(v.z); o.w = f2bf(v.w);
        *(u16x4*)(out + i) = o;
    }
}

// ---------------- cast + transpose: in[R][C] fp32 -> out[C][R] bf16 ----------------
__global__ void transpose_cast(const float* __restrict__ in, u16* __restrict__ out, int R, int C) {
    __shared__ float tile[32][33];
    int c0 = blockIdx.x * 32;
    int r0 = blockIdx.y * 32;
    int tx = threadIdx.x, ty = threadIdx.y;   // 32 x 8
#pragma unroll
    for (int i = 0; i < 32; i += 8)
        tile[ty + i][tx] = in[(size_t)(r0 + ty + i) * C + c0 + tx];
    __syncthreads();
#pragma unroll
    for (int i = 0; i < 32; i += 8)
        out[(size_t)(c0 + ty + i) * R + r0 + tx] = f2bf(tile[tx][ty + i]);
}

// ---------------- GEMM: C[M,N] = A[M,K](bf16) * Bt[N,K](bf16)^T + bias ----------------
// V^T epilogue via per-wave LDS transpose (coalesced dwordx4 stores).
template <int EPI>
__global__ __launch_bounds__(256) void gemm_bt(
    const u16* __restrict__ A, const u16* __restrict__ Bt,
    int K, int N, const float* __restrict__ bias,
    u16* __restrict__ Qb, u16* __restrict__ Kb, u16* __restrict__ Vtb,
    float* __restrict__ Cout)
{
    __shared__ __align__(16) u16 As[128 * 32];
    __shared__ __align__(16) u16 Bs[128 * 32];
    __shared__ __align__(16) u16 vtr[EPI == 0 ? 4 * 64 * 72 : 4];

    const int tid  = threadIdx.x;
    const int lane = tid & 63;
    const int wave = tid >> 6;
    const int wm = (wave >> 1) * 64;
    const int wn = (wave & 1) * 64;
    const int l15 = lane & 15;
    const int l4  = lane >> 4;
    const int bm = blockIdx.x * 128;
    const int bn = blockIdx.y * 128;

    f32x4 acc[4][4];
#pragma unroll
    for (int i = 0; i < 4; i++)
#pragma unroll
        for (int j = 0; j < 4; j++)
            acc[i][j] = (f32x4){0.f, 0.f, 0.f, 0.f};

    const int r0 = tid >> 2;
    const int cc = (tid & 3) * 8;
    const u16* Ap = A + (size_t)(bm + r0) * K + cc;
    const u16* Bp = Bt + (size_t)(bn + r0) * K + cc;
    u16* AsW = As + wave * 512;
    u16* BsW = Bs + wave * 512;

    for (int k0 = 0; k0 < K; k0 += 32) {
        __syncthreads();
        gll16(Ap + k0, AsW);
        gll16(Ap + (size_t)64 * K + k0, AsW + 2048);
        gll16(Bp + k0, BsW);
        gll16(Bp + (size_t)64 * K + k0, BsW + 2048);
        __syncthreads();

        bf16x8 af[4];
#pragma unroll
        for (int mi = 0; mi < 4; mi++)
            af[mi] = *(const bf16x8*)&As[(wm + mi * 16 + l15) * 32 + l4 * 8];
#pragma unroll
        for (int ni = 0; ni < 4; ni++) {
            bf16x8 bf = *(const bf16x8*)&Bs[(wn + ni * 16 + l15) * 32 + l4 * 8];
#pragma unroll
            for (int mi = 0; mi < 4; mi++)
                acc[mi][ni] = __builtin_amdgcn_mfma_f32_16x16x32_bf16(af[mi], bf, acc[mi][ni], 0, 0, 0);
        }
    }

    if (EPI == 0 && blockIdx.y >= 16) {
        u16* tr = vtr + wave * (64 * 72);
#pragma unroll
        for (int mi = 0; mi < 4; mi++)
#pragma unroll
            for (int ni = 0; ni < 4; ni++)
#pragma unroll
                for (int r = 0; r < 4; r++) {
                    int d  = ni * 16 + l15;
                    int tl = mi * 16 + l4 * 4 + r;
                    int gn = bn + wn + ni * 16 + l15;
                    tr[d * 72 + tl] = f2bf(acc[mi][ni][r] + bias[gn]);
                }
        __syncthreads();
        const int hh = (bn + wn - 2048) >> 6;
        const int bb = (bm + wm) >> 11;
        const int tglob0 = (bm + wm) & 2047;
        const int t0 = (lane & 7) * 8;
#pragma unroll
        for (int it = 0; it < 8; it++) {
            int d = it * 8 + (lane >> 3);
            uint4 v = *(const uint4*)&tr[d * 72 + t0];
            *(uint4*)(Vtb + (((size_t)(bb * 16 + hh)) * 64 + d) * 2048 + tglob0 + t0) = v;
        }
        return;
    }

#pragma unroll
    for (int mi = 0; mi < 4; mi++) {
#pragma unroll
        for (int ni = 0; ni < 4; ni++) {
#pragma unroll
            for (int r = 0; r < 4; r++) {
                int gm = bm + wm + mi * 16 + l4 * 4 + r;
                int gn = bn + wn + ni * 16 + l15;
                float v = acc[mi][ni][r] + bias[gn];
                if (EPI == 0) {
                    int s = gn >> 10, rem = gn & 1023;
                    int h = rem >> 6, d = rem & 63;
                    int b = gm >> 11, t = gm & 2047;
                    size_t qkidx = (((size_t)(b * 16 + h)) * 2048 + t) * 64 + d;
                    if (s == 0)      Qb[qkidx] = f2bf(v * 0.125f);
                    else             Kb[qkidx] = f2bf(v);
                } else {
                    Cout[(size_t)gm * N + gn] = v;
                }
            }
        }
    }
}

// ---------------- flash attention (causal), S^T formulation, split-kv ----------------
// Round 7: no-max softmax => kv-partials are PURE SUMS (no rescale). Split
// qb>=8 q-tiles into 2 balanced kv-chunks -> 24 chunks/bh (len 1..8, table
// in descending length = heavy-first dispatch). Grid 1536 = 6 blocks/CU vs
// LDS residency cap of 4 -> 2 backfill blocks keep occupancy at the cap
// (round 6: residency decayed 4->1 with no backfill, 19% occupancy).
// Split chunks write f32 (Ot,L) partials; attn_reduce sums+normalizes.
__device__ const unsigned char CH_QB[24] = {15,15,14, 7,14,13,13,12, 6,12,11,11,10, 5,10, 9, 9, 8, 4, 8, 3, 2, 1, 0};
__device__ const unsigned char CH_J0[24] = { 0, 8, 0, 0, 8, 0, 7, 0, 0, 7, 0, 6, 0, 0, 6, 0, 5, 0, 0, 5, 0, 0, 0, 0};
__device__ const unsigned char CH_J1[24] = { 7,15, 7, 7,14, 6,13, 6, 6,12, 5,11, 5, 5,10, 4, 9, 4, 4, 8, 3, 2, 1, 0};

#define KS_STR 72
#define VS_STR 136
__global__ __launch_bounds__(256) void attn_kernel(
    const u16* __restrict__ Qb, const u16* __restrict__ Kb,
    const u16* __restrict__ Vtb, u16* __restrict__ Ob,
    float* __restrict__ Opart, float* __restrict__ Lpart)
{
    const int blk   = blockIdx.x;
    const int chunk = blk >> 6;
    const int bh    = blk & 63;
    const int qb = CH_QB[chunk];
    const int j0 = CH_J0[chunk];
    const int j1 = CH_J1[chunk];
    const int b  = bh >> 4;
    const int h  = bh & 15;
    const u16* Qh = Qb + ((size_t)bh) * 2048 * 64;
    const u16* Kh = Kb + ((size_t)bh) * 2048 * 64;
    const u16* Vh = Vtb + ((size_t)bh) * 64 * 2048;

    __shared__ __align__(16) u16 Ks[128 * KS_STR];
    __shared__ __align__(16) u16 Vs[64 * VS_STR];

    const int tid  = threadIdx.x;
    const int wave = tid >> 6;
    const int lane = tid & 63;
    const int l15 = lane & 15;
    const int l4  = lane >> 4;

    // bpermute source byte-addresses (fixed permutation)
    const int addr_a = (((l4 & 1) * 32) + l15) * 4;
    const int addr_b = addr_a + 64;
    const bool hi_t  = (l4 & 2) != 0;

    const bf16x8 ones = __builtin_bit_cast(bf16x8,
        (u32x4){0x3F803F80u, 0x3F803F80u, 0x3F803F80u, 0x3F803F80u});

    const int qrow0 = qb * 128 + wave * 32;

    // Q B-frags: B[n=q][k=d]
    bf16x8 qf[2][2];
#pragma unroll
    for (int mi = 0; mi < 2; mi++)
#pragma unroll
        for (int kd = 0; kd < 2; kd++)
            qf[mi][kd] = *(const bf16x8*)(Qh + (size_t)(qrow0 + mi * 16 + l15) * 64 + kd * 32 + l4 * 8);

    f32x4 Ot[4][2];   // [d-tile][q-tile]
#pragma unroll
    for (int md = 0; md < 4; md++)
#pragma unroll
        for (int mi = 0; mi < 2; mi++)
            Ot[md][mi] = (f32x4){0.f, 0.f, 0.f, 0.f};
    f32x4 L[2];
    L[0] = (f32x4){0.f, 0.f, 0.f, 0.f};
    L[1] = (f32x4){0.f, 0.f, 0.f, 0.f};

    // prefetch tile j0
    uint4 kr[4], vr[4];
#pragma unroll
    for (int i = 0; i < 4; i++) {
        int c = tid + 256 * i;
        kr[i] = *(const uint4*)(Kh + (size_t)(j0 * 128 + (c >> 3)) * 64 + (c & 7) * 8);
        vr[i] = *(const uint4*)(Vh + (size_t)(c >> 4) * 2048 + j0 * 128 + (c & 15) * 8);
    }

    for (int j = j0; j <= j1; ++j) {
        __syncthreads();
#pragma unroll
        for (int i = 0; i < 4; i++) {
            int c = tid + 256 * i;
            *(uint4*)&Ks[(c >> 3) * KS_STR + (c & 7) * 8] = kr[i];
            *(uint4*)&Vs[(c >> 4) * VS_STR + (c & 15) * 8] = vr[i];
        }
        __syncthreads();

        if (j < j1) {
#pragma unroll
            for (int i = 0; i < 4; i++) {
                int c = tid + 256 * i;
                kr[i] = *(const uint4*)(Kh + (size_t)((j + 1) * 128 + (c >> 3)) * 64 + (c & 7) * 8);
                vr[i] = *(const uint4*)(Vh + (size_t)(c >> 4) * 2048 + (j + 1) * 128 + (c & 15) * 8);
            }
        }

        const bool diag = (j == qb);

        // Fused per 32-kv chunk: S^T (K*Q^T) -> exp -> pack -> bpermute -> PV
#pragma unroll
        for (int kk = 0; kk < 4; kk++) {
            uint32_t pk[2][2][2];   // [tt][mi][pair]
#pragma unroll
            for (int tt = 0; tt < 2; tt++) {
                const int t = kk * 2 + tt;
                f32x4 St[2];
                St[0] = (f32x4){0.f, 0.f, 0.f, 0.f};
                St[1] = (f32x4){0.f, 0.f, 0.f, 0.f};
#pragma unroll
                for (int kd = 0; kd < 2; kd++) {
                    bf16x8 kf = *(const bf16x8*)&Ks[(t * 16 + l15) * KS_STR + kd * 32 + l4 * 8];
                    St[0] = __builtin_amdgcn_mfma_f32_16x16x32_bf16(kf, qf[0][kd], St[0], 0, 0, 0);
                    St[1] = __builtin_amdgcn_mfma_f32_16x16x32_bf16(kf, qf[1][kd], St[1], 0, 0, 0);
                }
#pragma unroll
                for (int mi = 0; mi < 2; mi++) {
                    int qloc = wave * 32 + mi * 16 + l15;
                    float p[4];
#pragma unroll
                    for (int r = 0; r < 4; r++) {
                        float s = St[mi][r];
                        if (diag) {
                            int kvloc = t * 16 + l4 * 4 + r;
                            if (kvloc > qloc) s = -__builtin_inff();
                        }
                        p[r] = __expf(s);
                    }
                    union { float f; uint32_t u; } u0, u1, u2, u3;
                    u0.f = p[0]; u1.f = p[1]; u2.f = p[2]; u3.f = p[3];
                    pk[tt][mi][0] = __builtin_amdgcn_perm(u1.u, u0.u, 0x07060302u);
                    pk[tt][mi][1] = __builtin_amdgcn_perm(u3.u, u2.u, 0x07060302u);
                }
            }

            bf16x8 vtf[4];
#pragma unroll
            for (int md = 0; md < 4; md++)
                vtf[md] = *(const bf16x8*)&Vs[(md * 16 + l15) * VS_STR + kk * 32 + l4 * 8];
#pragma unroll
            for (int mi = 0; mi < 2; mi++) {
                uint32_t s0a = __builtin_amdgcn_ds_bpermute(addr_a, pk[0][mi][0]);
                uint32_t s0b = __builtin_amdgcn_ds_bpermute(addr_a, pk[1][mi][0]);
                uint32_t s1a = __builtin_amdgcn_ds_bpermute(addr_a, pk[0][mi][1]);
                uint32_t s1b = __builtin_amdgcn_ds_bpermute(addr_a, pk[1][mi][1]);
                uint32_t s2a = __builtin_amdgcn_ds_bpermute(addr_b, pk[0][mi][0]);
                uint32_t s2b = __builtin_amdgcn_ds_bpermute(addr_b, pk[1][mi][0]);
                uint32_t s3a = __builtin_amdgcn_ds_bpermute(addr_b, pk[0][mi][1]);
                uint32_t s3b = __builtin_amdgcn_ds_bpermute(addr_b, pk[1][mi][1]);
                u32x4 pt;
                pt.x = hi_t ? s0b : s0a;
                pt.y = hi_t ? s1b : s1a;
                pt.z = hi_t ? s2b : s2a;
                pt.w = hi_t ? s3b : s3a;
                bf16x8 ptf = __builtin_bit_cast(bf16x8, pt);
#pragma unroll
                for (int md = 0; md < 4; md++)
                    Ot[md][mi] = __builtin_amdgcn_mfma_f32_16x16x32_bf16(vtf[md], ptf, Ot[md][mi], 0, 0, 0);
                L[mi] = __builtin_amdgcn_mfma_f32_16x16x32_bf16(ones, ptf, L[mi], 0, 0, 0);
            }
        }
    }

    if (j0 == 0 && j1 == qb) {
        // single-chunk q-tile: normalize + final store
#pragma unroll
        for (int mi = 0; mi < 2; mi++) {
            float inv = 1.0f / L[mi][0];
            int t = qrow0 + mi * 16 + l15;
#pragma unroll
            for (int md = 0; md < 4; md++) {
                u16x4 o;
                o.x = f2bf(Ot[md][mi][0] * inv);
                o.y = f2bf(Ot[md][mi][1] * inv);
                o.z = f2bf(Ot[md][mi][2] * inv);
                o.w = f2bf(Ot[md][mi][3] * inv);
                *(u16x4*)(Ob + ((size_t)(b * 2048 + t)) * 1024 + h * 64 + md * 16 + l4 * 4) = o;
            }
        }
    } else {
        // split chunk: dump raw f32 partials (pure sums; combined in reduce)
        const int c = (j0 == 0) ? 0 : 1;
        const int pidx = (bh * 8 + (qb - 8)) * 2 + c;
        float* Op = Opart + (size_t)pidx * 8192;
#pragma unroll
        for (int md = 0; md < 4; md++)
#pragma unroll
            for (int mi = 0; mi < 2; mi++)
                *(f32x4*)(Op + (tid * 8 + md * 2 + mi) * 4) = Ot[md][mi];
#pragma unroll
        for (int mi = 0; mi < 2; mi++)
            Lpart[pidx * 128 + wave * 32 + mi * 16 + l15] = L[mi][0];
    }
}

// combine split-kv partials: O = (O0+O1)/(L0+L1), store bf16
__global__ __launch_bounds__(256) void attn_reduce(
    const float* __restrict__ Opart, const float* __restrict__ Lpart,
    u16* __restrict__ Ob)
{
    const int blk = blockIdx.x;        // 512 = 64 bh x 8 split q-tiles
    const int bh = blk >> 3;
    const int qr = blk & 7;
    const int qb = 8 + qr;
    const int b  = bh >> 4;
    const int h  = bh & 15;
    const int base = (bh * 8 + qr) * 2;
    const int tid = threadIdx.x;
    const int wave = tid >> 6;
    const int lane = tid & 63;
    const int l15 = lane & 15;
    const int l4  = lane >> 4;

    const float* O0 = Opart + (size_t)base * 8192;
    const float* O1 = O0 + 8192;

    float linv[2];
#pragma unroll
    for (int mi = 0; mi < 2; mi++) {
        int wq = wave * 32 + mi * 16 + l15;
        linv[mi] = 1.0f / (Lpart[base * 128 + wq] + Lpart[(base + 1) * 128 + wq]);
    }
#pragma unroll
    for (int md = 0; md < 4; md++)
#pragma unroll
        for (int mi = 0; mi < 2; mi++) {
            int o = (tid * 8 + md * 2 + mi) * 4;
            f32x4 v = *(const f32x4*)(O0 + o) + *(const f32x4*)(O1 + o);
            int t = qb * 128 + wave * 32 + mi * 16 + l15;
            u16x4 ov;
            ov.x = f2bf(v.x * linv[mi]);
            ov.y = f2bf(v.y * linv[mi]);
            ov.z = f2bf(v.z * linv[mi]);
            ov.w = f2bf(v.w * linv[mi]);
            *(u16x4*)(Ob + ((size_t)(b * 2048 + t)) * 1024 + h * 64 + md * 16 + l4 * 4) = ov;
        }
}

extern "C" void kernel_launch(void* const* d_in, const int* in_sizes, int n_in,
                              void* d_out, int out_size, void* d_ws, size_t ws_size,
                              hipStream_t stream) {
    const float* x     = (const float*)d_in[0];
    const float* w_qkv = (const float*)d_in[1];
    const float* b_qkv = (const float*)d_in[2];
    const float* w_out = (const float*)d_in[3];
    const float* b_out = (const float*)d_in[4];
    float* out = (float*)d_out;

    size_t off = 0;
    char* ws = (char*)d_ws;
    auto alloc = [&](size_t bytes) -> void* {
        void* p = ws + off;
        off += (bytes + 255) & ~(size_t)255;
        return p;
    };
    u16* xb    = (u16*)alloc((size_t)8192 * 1024 * 2);
    u16* wqkvT = (u16*)alloc((size_t)3072 * 1024 * 2);
    u16* woutT = (u16*)alloc((size_t)1024 * 1024 * 2);
    u16* Qb    = (u16*)alloc((size_t)8192 * 1024 * 2);   // [B,H,T,Dh]
    u16* Kb    = (u16*)alloc((size_t)8192 * 1024 * 2);   // [B,H,T,Dh]
    u16* Vtb   = (u16*)alloc((size_t)8192 * 1024 * 2);   // [B,H,Dh,T]
    float* Opart = (float*)alloc((size_t)1024 * 8192 * 4);  // 33.5 MB split partials
    float* Lpart = (float*)alloc((size_t)1024 * 128 * 4);
    u16* Ob    = xb;  // reuse x_bf16 after GEMM1 consumed it

    cast_kernel<<<dim3(8192), dim3(256), 0, stream>>>(x, xb, 8192 * 1024);
    transpose_cast<<<dim3(3072 / 32, 1024 / 32), dim3(32, 8), 0, stream>>>(w_qkv, wqkvT, 1024, 3072);
    transpose_cast<<<dim3(1024 / 32, 1024 / 32), dim3(32, 8), 0, stream>>>(w_out, woutT, 1024, 1024);

    gemm_bt<0><<<dim3(64, 24), dim3(256), 0, stream>>>(xb, wqkvT, 1024, 3072, b_qkv, Qb, Kb, Vtb, nullptr);
    attn_kernel<<<dim3(1536), dim3(256), 0, stream>>>(Qb, Kb, Vtb, Ob, Opart, Lpart);
    attn_reduce<<<dim3(512), dim3(256), 0, stream>>>(Opart, Lpart, Ob);
    gemm_bt<1><<<dim3(64, 8), dim3(256), 0, stream>>>(Ob, woutT, 1024, 1024, b_out, nullptr, nullptr, nullptr, out);
}

// Round 9
// 270.203 us; speedup vs baseline: 1.2409x; 1.2409x over previous
//
#include <hip/hip_runtime.h>
#include <stdint.h>

typedef unsigned short u16;
typedef __attribute__((ext_vector_type(8))) __bf16 bf16x8;
typedef __attribute__((ext_vector_type(4))) float f32x4;
typedef __attribute__((ext_vector_type(4))) u16 u16x4;
typedef __attribute__((ext_vector_type(4))) uint32_t u32x4;

__device__ __forceinline__ u16 f2bf(float f) {
    union { float f; uint32_t u; } v; v.f = f;
    uint32_t r = (v.u + 0x7fffu + ((v.u >> 16) & 1u)) >> 16;
    return (u16)r;
}

__device__ __forceinline__ void gll16(const u16* g, u16* l) {
    __builtin_amdgcn_global_load_lds((const __attribute__((address_space(1))) uint32_t*)g,
                                     (__attribute__((address_space(3))) uint32_t*)l, 16, 0, 0);
}

// ---------------- cast fp32 -> bf16 (x) ----------------
__global__ void cast_kernel(const float* __restrict__ in, u16* __restrict__ out, int n) {
    int i = (blockIdx.x * blockDim.x + threadIdx.x) * 4;
    if (i + 3 < n) {
        float4 v = *(const float4*)(in + i);
        u16x4 o;
        o.x = f2bf(v.x); o.y = f2bf(v.y); o.z = f2bf(v.z); o.w = f2bf(v.w);
        *(u16x4*)(out + i) = o;
    }
}

// ---------------- cast + transpose: in[R][C] fp32 -> out[C][R] bf16 ----------------
__global__ void transpose_cast(const float* __restrict__ in, u16* __restrict__ out, int R, int C) {
    __shared__ float tile[32][33];
    int c0 = blockIdx.x * 32;
    int r0 = blockIdx.y * 32;
    int tx = threadIdx.x, ty = threadIdx.y;   // 32 x 8
#pragma unroll
    for (int i = 0; i < 32; i += 8)
        tile[ty + i][tx] = in[(size_t)(r0 + ty + i) * C + c0 + tx];
    __syncthreads();
#pragma unroll
    for (int i = 0; i < 32; i += 8)
        out[(size_t)(c0 + ty + i) * R + r0 + tx] = f2bf(tile[tx][ty + i]);
}

// ---------------- GEMM: C[M,N] = A[M,K](bf16) * Bt[N,K](bf16)^T + bias ----------------
// V^T epilogue via per-wave LDS transpose (coalesced dwordx4 stores).
template <int EPI>
__global__ __launch_bounds__(256) void gemm_bt(
    const u16* __restrict__ A, const u16* __restrict__ Bt,
    int K, int N, const float* __restrict__ bias,
    u16* __restrict__ Qb, u16* __restrict__ Kb, u16* __restrict__ Vtb,
    float* __restrict__ Cout)
{
    __shared__ __align__(16) u16 As[128 * 32];
    __shared__ __align__(16) u16 Bs[128 * 32];
    __shared__ __align__(16) u16 vtr[EPI == 0 ? 4 * 64 * 72 : 4];

    const int tid  = threadIdx.x;
    const int lane = tid & 63;
    const int wave = tid >> 6;
    const int wm = (wave >> 1) * 64;
    const int wn = (wave & 1) * 64;
    const int l15 = lane & 15;
    const int l4  = lane >> 4;
    const int bm = blockIdx.x * 128;
    const int bn = blockIdx.y * 128;

    f32x4 acc[4][4];
#pragma unroll
    for (int i = 0; i < 4; i++)
#pragma unroll
        for (int j = 0; j < 4; j++)
            acc[i][j] = (f32x4){0.f, 0.f, 0.f, 0.f};

    const int r0 = tid >> 2;
    const int cc = (tid & 3) * 8;
    const u16* Ap = A + (size_t)(bm + r0) * K + cc;
    const u16* Bp = Bt + (size_t)(bn + r0) * K + cc;
    u16* AsW = As + wave * 512;
    u16* BsW = Bs + wave * 512;

    for (int k0 = 0; k0 < K; k0 += 32) {
        __syncthreads();
        gll16(Ap + k0, AsW);
        gll16(Ap + (size_t)64 * K + k0, AsW + 2048);
        gll16(Bp + k0, BsW);
        gll16(Bp + (size_t)64 * K + k0, BsW + 2048);
        __syncthreads();

        bf16x8 af[4];
#pragma unroll
        for (int mi = 0; mi < 4; mi++)
            af[mi] = *(const bf16x8*)&As[(wm + mi * 16 + l15) * 32 + l4 * 8];
#pragma unroll
        for (int ni = 0; ni < 4; ni++) {
            bf16x8 bf = *(const bf16x8*)&Bs[(wn + ni * 16 + l15) * 32 + l4 * 8];
#pragma unroll
            for (int mi = 0; mi < 4; mi++)
                acc[mi][ni] = __builtin_amdgcn_mfma_f32_16x16x32_bf16(af[mi], bf, acc[mi][ni], 0, 0, 0);
        }
    }

    if (EPI == 0 && blockIdx.y >= 16) {
        u16* tr = vtr + wave * (64 * 72);
#pragma unroll
        for (int mi = 0; mi < 4; mi++)
#pragma unroll
            for (int ni = 0; ni < 4; ni++)
#pragma unroll
                for (int r = 0; r < 4; r++) {
                    int d  = ni * 16 + l15;
                    int tl = mi * 16 + l4 * 4 + r;
                    int gn = bn + wn + ni * 16 + l15;
                    tr[d * 72 + tl] = f2bf(acc[mi][ni][r] + bias[gn]);
                }
        __syncthreads();
        const int hh = (bn + wn - 2048) >> 6;
        const int bb = (bm + wm) >> 11;
        const int tglob0 = (bm + wm) & 2047;
        const int t0 = (lane & 7) * 8;
#pragma unroll
        for (int it = 0; it < 8; it++) {
            int d = it * 8 + (lane >> 3);
            uint4 v = *(const uint4*)&tr[d * 72 + t0];
            *(uint4*)(Vtb + (((size_t)(bb * 16 + hh)) * 64 + d) * 2048 + tglob0 + t0) = v;
        }
        return;
    }

#pragma unroll
    for (int mi = 0; mi < 4; mi++) {
#pragma unroll
        for (int ni = 0; ni < 4; ni++) {
#pragma unroll
            for (int r = 0; r < 4; r++) {
                int gm = bm + wm + mi * 16 + l4 * 4 + r;
                int gn = bn + wn + ni * 16 + l15;
                float v = acc[mi][ni][r] + bias[gn];
                if (EPI == 0) {
                    int s = gn >> 10, rem = gn & 1023;
                    int h = rem >> 6, d = rem & 63;
                    int b = gm >> 11, t = gm & 2047;
                    size_t qkidx = (((size_t)(b * 16 + h)) * 2048 + t) * 64 + d;
                    if (s == 0)      Qb[qkidx] = f2bf(v * 0.125f);
                    else             Kb[qkidx] = f2bf(v);
                } else {
                    Cout[(size_t)gm * N + gn] = v;
                }
            }
        }
    }
}

// ---------------- flash attention (causal), S^T formulation ----------------
// Round 8 result: extra TLP does nothing (127us @ both 1024 and 1536 blocks)
// -> bottleneck is the per-tile 2-barrier staging chain. Round 9: single
// barrier per tile via double-buffered K/V staged with global_load_lds
// (zero staging regs, no ds_writes, no mid-tile vmcnt waits; the vmcnt(0)
// drain at the barrier is fully covered by the tile compute). gll16 forces
// unpadded lane-contiguous LDS, so bank conflicts are killed with an XOR
// swizzle on 16B units: K (8 units/row): u^(r&7); V (16 units/row):
// u^(r&15). All fragment reads 2-way per 16-lane phase = free (m136);
// global sources stay 128B-coalesced.
__global__ __launch_bounds__(256) void attn_kernel(
    const u16* __restrict__ Qb, const u16* __restrict__ Kb,
    const u16* __restrict__ Vtb, u16* __restrict__ Ob)
{
    const int blk = blockIdx.x;
    const int qb  = 15 - (blk >> 6);
    const int bh  = blk & 63;
    const int b   = bh >> 4;
    const int h   = bh & 15;
    const u16* Qh = Qb + ((size_t)bh) * 2048 * 64;
    const u16* Kh = Kb + ((size_t)bh) * 2048 * 64;
    const u16* Vh = Vtb + ((size_t)bh) * 64 * 2048;

    __shared__ __align__(16) u16 KsBuf[2][128 * 64];   // swizzled
    __shared__ __align__(16) u16 VsBuf[2][64 * 128];   // swizzled

    const int tid  = threadIdx.x;
    const int wave = tid >> 6;
    const int lane = tid & 63;
    const int l15 = lane & 15;
    const int l4  = lane >> 4;

    // bpermute source byte-addresses (fixed permutation)
    const int addr_a = (((l4 & 1) * 32) + l15) * 4;
    const int addr_b = addr_a + 64;
    const bool hi_t  = (l4 & 2) != 0;

    const bf16x8 ones = __builtin_bit_cast(bf16x8,
        (u32x4){0x3F803F80u, 0x3F803F80u, 0x3F803F80u, 0x3F803F80u});

    const int qrow0 = qb * 128 + wave * 32;

    // async-stage tile j into buffer pb (4 K-units + 4 V-units per thread)
    auto stage = [&](int j, int pb) {
#pragma unroll
        for (int i = 0; i < 4; i++) {
            int lu = i * 256 + tid;               // unit index 0..1023
            int rK = lu >> 3, uK = (lu & 7) ^ (rK & 7);
            gll16(Kh + ((size_t)(j * 128 + rK)) * 64 + uK * 8,
                  &KsBuf[pb][(i * 256 + wave * 64) * 8]);
            int rV = lu >> 4, uV = (lu & 15) ^ (rV & 15);
            gll16(Vh + (size_t)rV * 2048 + j * 128 + uV * 8,
                  &VsBuf[pb][(i * 256 + wave * 64) * 8]);
        }
    };

    // Q B-frags: B[n=q][k=d]
    bf16x8 qf[2][2];
#pragma unroll
    for (int mi = 0; mi < 2; mi++)
#pragma unroll
        for (int kd = 0; kd < 2; kd++)
            qf[mi][kd] = *(const bf16x8*)(Qh + (size_t)(qrow0 + mi * 16 + l15) * 64 + kd * 32 + l4 * 8);

    f32x4 Ot[4][2];   // [d-tile][q-tile]
#pragma unroll
    for (int md = 0; md < 4; md++)
#pragma unroll
        for (int mi = 0; mi < 2; mi++)
            Ot[md][mi] = (f32x4){0.f, 0.f, 0.f, 0.f};
    f32x4 L[2];
    L[0] = (f32x4){0.f, 0.f, 0.f, 0.f};
    L[1] = (f32x4){0.f, 0.f, 0.f, 0.f};

    stage(0, 0);
    __syncthreads();   // compiler drains vmcnt(0) first

    int p = 0;
    for (int j = 0; j <= qb; ++j) {
        if (j < qb) stage(j + 1, p ^ 1);   // fully async; lands during compute

        const u16* Kc = KsBuf[p];
        const u16* Vc = VsBuf[p];
        const bool diag = (j == qb);

        // Fused per 32-kv chunk: S^T (K*Q^T) -> exp -> pack -> bpermute -> PV
#pragma unroll
        for (int kk = 0; kk < 4; kk++) {
            uint32_t pk[2][2][2];   // [tt][mi][pair]
#pragma unroll
            for (int tt = 0; tt < 2; tt++) {
                const int t = kk * 2 + tt;
                const int rr = t * 16 + l15;
                f32x4 St[2];
                St[0] = (f32x4){0.f, 0.f, 0.f, 0.f};
                St[1] = (f32x4){0.f, 0.f, 0.f, 0.f};
#pragma unroll
                for (int kd = 0; kd < 2; kd++) {
                    bf16x8 kf = *(const bf16x8*)&Kc[((rr << 3) + ((kd * 4 + l4) ^ (rr & 7))) * 8];
                    St[0] = __builtin_amdgcn_mfma_f32_16x16x32_bf16(kf, qf[0][kd], St[0], 0, 0, 0);
                    St[1] = __builtin_amdgcn_mfma_f32_16x16x32_bf16(kf, qf[1][kd], St[1], 0, 0, 0);
                }
#pragma unroll
                for (int mi = 0; mi < 2; mi++) {
                    int qloc = wave * 32 + mi * 16 + l15;
                    float pr[4];
#pragma unroll
                    for (int r = 0; r < 4; r++) {
                        float s = St[mi][r];
                        if (diag) {
                            int kvloc = t * 16 + l4 * 4 + r;
                            if (kvloc > qloc) s = -__builtin_inff();
                        }
                        pr[r] = __expf(s);
                    }
                    union { float f; uint32_t u; } u0, u1, u2, u3;
                    u0.f = pr[0]; u1.f = pr[1]; u2.f = pr[2]; u3.f = pr[3];
                    pk[tt][mi][0] = __builtin_amdgcn_perm(u1.u, u0.u, 0x07060302u);
                    pk[tt][mi][1] = __builtin_amdgcn_perm(u3.u, u2.u, 0x07060302u);
                }
            }

            bf16x8 vtf[4];
#pragma unroll
            for (int md = 0; md < 4; md++) {
                const int rr = md * 16 + l15;
                vtf[md] = *(const bf16x8*)&Vc[((rr << 4) + ((kk * 4 + l4) ^ (rr & 15))) * 8];
            }
#pragma unroll
            for (int mi = 0; mi < 2; mi++) {
                uint32_t s0a = __builtin_amdgcn_ds_bpermute(addr_a, pk[0][mi][0]);
                uint32_t s0b = __builtin_amdgcn_ds_bpermute(addr_a, pk[1][mi][0]);
                uint32_t s1a = __builtin_amdgcn_ds_bpermute(addr_a, pk[0][mi][1]);
                uint32_t s1b = __builtin_amdgcn_ds_bpermute(addr_a, pk[1][mi][1]);
                uint32_t s2a = __builtin_amdgcn_ds_bpermute(addr_b, pk[0][mi][0]);
                uint32_t s2b = __builtin_amdgcn_ds_bpermute(addr_b, pk[1][mi][0]);
                uint32_t s3a = __builtin_amdgcn_ds_bpermute(addr_b, pk[0][mi][1]);
                uint32_t s3b = __builtin_amdgcn_ds_bpermute(addr_b, pk[1][mi][1]);
                u32x4 pt;
                pt.x = hi_t ? s0b : s0a;
                pt.y = hi_t ? s1b : s1a;
                pt.z = hi_t ? s2b : s2a;
                pt.w = hi_t ? s3b : s3a;
                bf16x8 ptf = __builtin_bit_cast(bf16x8, pt);
#pragma unroll
                for (int md = 0; md < 4; md++)
                    Ot[md][mi] = __builtin_amdgcn_mfma_f32_16x16x32_bf16(vtf[md], ptf, Ot[md][mi], 0, 0, 0);
                L[mi] = __builtin_amdgcn_mfma_f32_16x16x32_bf16(ones, ptf, L[mi], 0, 0, 0);
            }
        }

        __syncthreads();   // drains the async stage (vmcnt 0) + flips buffer
        p ^= 1;
    }

    // epilogue: O^T/l -> Ob[B*T, 1024]; pack 4 consecutive d -> 8B store
#pragma unroll
    for (int mi = 0; mi < 2; mi++) {
        float inv = 1.0f / L[mi][0];
        int t = qrow0 + mi * 16 + l15;
#pragma unroll
        for (int md = 0; md < 4; md++) {
            u16x4 o;
            o.x = f2bf(Ot[md][mi][0] * inv);
            o.y = f2bf(Ot[md][mi][1] * inv);
            o.z = f2bf(Ot[md][mi][2] * inv);
            o.w = f2bf(Ot[md][mi][3] * inv);
            *(u16x4*)(Ob + ((size_t)(b * 2048 + t)) * 1024 + h * 64 + md * 16 + l4 * 4) = o;
        }
    }
}

extern "C" void kernel_launch(void* const* d_in, const int* in_sizes, int n_in,
                              void* d_out, int out_size, void* d_ws, size_t ws_size,
                              hipStream_t stream) {
    const float* x     = (const float*)d_in[0];
    const float* w_qkv = (const float*)d_in[1];
    const float* b_qkv = (const float*)d_in[2];
    const float* w_out = (const float*)d_in[3];
    const float* b_out = (const float*)d_in[4];
    float* out = (float*)d_out;

    size_t off = 0;
    char* ws = (char*)d_ws;
    auto alloc = [&](size_t bytes) -> void* {
        void* p = ws + off;
        off += (bytes + 255) & ~(size_t)255;
        return p;
    };
    u16* xb    = (u16*)alloc((size_t)8192 * 1024 * 2);
    u16* wqkvT = (u16*)alloc((size_t)3072 * 1024 * 2);
    u16* woutT = (u16*)alloc((size_t)1024 * 1024 * 2);
    u16* Qb    = (u16*)alloc((size_t)8192 * 1024 * 2);   // [B,H,T,Dh]
    u16* Kb    = (u16*)alloc((size_t)8192 * 1024 * 2);   // [B,H,T,Dh]
    u16* Vtb   = (u16*)alloc((size_t)8192 * 1024 * 2);   // [B,H,Dh,T]
    u16* Ob    = xb;  // reuse x_bf16 after GEMM1 consumed it

    cast_kernel<<<dim3(8192), dim3(256), 0, stream>>>(x, xb, 8192 * 1024);
    transpose_cast<<<dim3(3072 / 32, 1024 / 32), dim3(32, 8), 0, stream>>>(w_qkv, wqkvT, 1024, 3072);
    transpose_cast<<<dim3(1024 / 32, 1024 / 32), dim3(32, 8), 0, stream>>>(w_out, woutT, 1024, 1024);

    gemm_bt<0><<<dim3(64, 24), dim3(256), 0, stream>>>(xb, wqkvT, 1024, 3072, b_qkv, Qb, Kb, Vtb, nullptr);
    attn_kernel<<<dim3(1024), dim3(256), 0, stream>>>(Qb, Kb, Vtb, Ob);
    gemm_bt<1><<<dim3(64, 8), dim3(256), 0, stream>>>(Ob, woutT, 1024, 1024, b_out, nullptr, nullptr, nullptr, out);
}